// Round 5
// baseline (247.720 us; speedup 1.0000x reference)
//
#include <hip/hip_runtime.h>
#include <math.h>

// Problem constants (from reference setup_inputs)
#define NB        4096
#define NH        200
#define HIST_ROWS 100000
#define REG_ROWS  1000
#define NTILES    13        // ceil(200/16) M-tiles, M=208

typedef __attribute__((ext_vector_type(8))) short short8;  // 8 bf16 = 4 VGPRs (MFMA A/B frag)
typedef __attribute__((ext_vector_type(4))) float f32x4;   // MFMA C/D frag

// fp32 -> bf16 round-to-nearest-even
__device__ __forceinline__ unsigned short f2bf(float x) {
    union { float f; unsigned u; } v; v.f = x;
    unsigned r = v.u + 0x7FFF + ((v.u >> 16) & 1);
    return (unsigned short)(r >> 16);
}

// Prepass: (a) convert W_hist|W_reg to bf16 tables (concat layout) in ws,
// (b) block 0 additionally emits W1F = W1 pre-shuffled into MFMA-fragment
// order (fp32, 32 KB): chunk i=(frag,c) with frag=nt*4+ks (nt<4), c=q*16+l,
// elems j=0..7 -> W1[(ks*32+q*8+j)*64 + nt*16+l]. Per-block B' build then
// reads W1F fully coalesced.
__global__ __launch_bounds__(256) void prep_tables(
    const float* __restrict__ Wh, const float* __restrict__ Wr,
    const float* __restrict__ W1,
    unsigned short* __restrict__ tab, float* __restrict__ W1F)
{
    const int total4 = (HIST_ROWS + REG_ROWS) * 16;   // float4s
    const int HE4    = HIST_ROWS * 16;
    for (int i = blockIdx.x * blockDim.x + threadIdx.x; i < total4;
         i += gridDim.x * blockDim.x) {
        const float4 v = (i < HE4) ? ((const float4*)Wh)[i]
                                   : ((const float4*)Wr)[i - HE4];
        ushort4 o;
        o.x = f2bf(v.x); o.y = f2bf(v.y); o.z = f2bf(v.z); o.w = f2bf(v.w);
        ((ushort4*)tab)[i] = o;
    }
    if (blockIdx.x == 0) {
        for (int i = threadIdx.x; i < 1024; i += 256) {
            const int frag = i >> 6, c = i & 63;
            const int nt = frag >> 2, ks = frag & 3, q = c >> 4, l = c & 15;
            const int k0 = ks * 32 + q * 8, n = nt * 16 + l;
            float tmp[8];
            #pragma unroll
            for (int j = 0; j < 8; ++j) tmp[j] = W1[(k0 + j) * 64 + n];
            float4* dst = (float4*)(W1F + i * 8);
            dst[0] = make_float4(tmp[0], tmp[1], tmp[2], tmp[3]);
            dst[1] = make_float4(tmp[4], tmp[5], tmp[6], tmp[7]);
        }
    }
}

// One block per b. Algebra: inp@W1 = h@(diag(t)W1), s_j = h_j.t, so
// B' = [t(x)W1 | t-col] built per block from W1F (coalesced) into LDS in
// fragment order; A = raw bf16 gathered rows from the prepass table.
// Each wave owns up to 2 M-tiles per outer iteration (acc = 2x5x4 = 40 AGPRs,
// keeps VGPR+AGPR <= 128 for 4 waves/SIMD). Tiles: iter0 {wv, wv+4},
// iter1 {wv+8, wv+12<13}.
template <bool BT>
__global__ __launch_bounds__(256, 4) void nais_mfma4(
    const int*   __restrict__ history,
    const int*   __restrict__ target,
    const int*   __restrict__ history_region,
    const int*   __restrict__ target_region,
    const float* __restrict__ W_hist,
    const float* __restrict__ W_tgt,
    const float* __restrict__ W_reg,
    const float* __restrict__ W1,
    const float* __restrict__ b1,
    const float* __restrict__ W2,
    const unsigned short* __restrict__ tab,   // bf16 tables (BT)
    const float* __restrict__ W1F,            // fragment-ordered W1 (BT)
    float*       __restrict__ out)
{
    __shared__ int hist_lds[224];
    __shared__ int hreg_lds[224];
    __shared__ __align__(16) float t_lds[128];
    __shared__ __align__(16) unsigned short Bf[20 * 512];   // 20 frags x 64 chunks x 8 bf16
    __shared__ float logit_lds[208];
    __shared__ float s_lds[208];
    __shared__ float red_e[4], red_p[4];

    const int b   = blockIdx.x;
    const int tid = threadIdx.x;
    const int tgt = target[b];

    // ---- stage indices (rows 200..207 dup row 199) and t ----
    if (tid < 224) {
        const int jj = tid < NH ? tid : NH - 1;
        hist_lds[tid] = history[b * NH + jj];
        hreg_lds[tid] = history_region[b * NH + jj];
    }
    if (tid < 64) {
        t_lds[tid] = W_tgt[(size_t)tgt * 64 + tid];
    } else if (tid < 128) {
        t_lds[tid] = W_reg[(size_t)target_region[b] * 64 + (tid - 64)];
    }
    __syncthreads();

    // ---- build B' fragments: frags 0..15 (t (x) W1), frags 16..19 (t col) ----
    #pragma unroll
    for (int v = 0; v < 4; ++v) {
        const int i  = tid + v * 256;               // chunk 0..1023
        const int ks = (i >> 6) & 3, q = (i >> 4) & 3;
        const int k0 = ks * 32 + q * 8;
        const float4 t0 = *(const float4*)(t_lds + k0);
        const float4 t1 = *(const float4*)(t_lds + k0 + 4);
        float4 w0, w1;
        if (BT) {
            w0 = ((const float4*)W1F)[i * 2];
            w1 = ((const float4*)W1F)[i * 2 + 1];
        } else {
            const int nt = i >> 8, l = i & 15, n = nt * 16 + l;
            float tmp[8];
            #pragma unroll
            for (int j = 0; j < 8; ++j) tmp[j] = W1[(k0 + j) * 64 + n];
            w0 = make_float4(tmp[0], tmp[1], tmp[2], tmp[3]);
            w1 = make_float4(tmp[4], tmp[5], tmp[6], tmp[7]);
        }
        short8 o;
        o[0] = (short)f2bf(w0.x * t0.x); o[1] = (short)f2bf(w0.y * t0.y);
        o[2] = (short)f2bf(w0.z * t0.z); o[3] = (short)f2bf(w0.w * t0.w);
        o[4] = (short)f2bf(w1.x * t1.x); o[5] = (short)f2bf(w1.y * t1.y);
        o[6] = (short)f2bf(w1.z * t1.z); o[7] = (short)f2bf(w1.w * t1.w);
        *reinterpret_cast<short8*>(&Bf[i * 8]) = o;
    }
    {   // t-column: chunks 1024..1279, one per thread
        const int i  = 1024 + tid;
        const int ks = tid >> 6, c = tid & 63, q = c >> 4, l = c & 15;
        const int k0 = ks * 32 + q * 8;
        short8 o;
        #pragma unroll
        for (int j = 0; j < 8; ++j)
            o[j] = (l == 0) ? (short)f2bf(t_lds[k0 + j]) : (short)0;
        *reinterpret_cast<short8*>(&Bf[i * 8]) = o;
    }
    __syncthreads();

    const int lane = tid & 63, wv = tid >> 6;
    const int l15  = lane & 15, quad = lane >> 4;

    float w2v[4], b1v[4];
    #pragma unroll
    for (int nt = 0; nt < 4; ++nt) {
        w2v[nt] = W2[nt * 16 + l15];
        b1v[nt] = b1[nt * 16 + l15];
    }

    const unsigned short* tabr = tab + (size_t)HIST_ROWS * 64;

    #pragma unroll 1
    for (int it = 0; it < 2; ++it) {
        const int  tl0  = wv + it * 8;
        const int  tl1  = tl0 + 4;
        const bool has1 = (tl1 < NTILES);

        const int j0 = tl0 * 16 + l15;
        const int j1 = has1 ? (tl1 * 16 + l15) : j0;

        const unsigned short *p0h, *p0r, *p1h, *p1r;
        const float *f0h, *f0r, *f1h, *f1r;
        if (BT) {
            p0h = tab  + (size_t)hist_lds[j0] * 64 + quad * 8;
            p0r = tabr + (size_t)hreg_lds[j0] * 64 + quad * 8;
            p1h = tab  + (size_t)hist_lds[j1] * 64 + quad * 8;
            p1r = tabr + (size_t)hreg_lds[j1] * 64 + quad * 8;
        } else {
            f0h = W_hist + (size_t)hist_lds[j0] * 64 + quad * 8;
            f0r = W_reg  + (size_t)hreg_lds[j0] * 64 + quad * 8;
            f1h = W_hist + (size_t)hist_lds[j1] * 64 + quad * 8;
            f1r = W_reg  + (size_t)hreg_lds[j1] * 64 + quad * 8;
        }

        f32x4 acc[2][5];
        #pragma unroll
        for (int tt = 0; tt < 2; ++tt)
            #pragma unroll
            for (int nt = 0; nt < 5; ++nt) acc[tt][nt] = (f32x4){0.f, 0.f, 0.f, 0.f};

        #pragma unroll
        for (int ks = 0; ks < 4; ++ks) {
            short8 bf[5];
            #pragma unroll
            for (int nt = 0; nt < 5; ++nt)
                bf[nt] = *reinterpret_cast<const short8*>(
                    &Bf[((nt * 4 + ks) * 64 + quad * 16 + l15) * 8]);

            short8 a0, a1;
            if (BT) {
                a0 = *reinterpret_cast<const short8*>(
                        (ks < 2 ? p0h : p0r) + (ks & 1) * 32);
                a1 = *reinterpret_cast<const short8*>(
                        (ks < 2 ? p1h : p1r) + (ks & 1) * 32);
            } else {
                const float* q0 = (ks < 2 ? f0h : f0r) + (ks & 1) * 32;
                const float* q1 = (ks < 2 ? f1h : f1r) + (ks & 1) * 32;
                const float4 v0 = *(const float4*)q0, v1 = *(const float4*)(q0 + 4);
                const float4 u0 = *(const float4*)q1, u1 = *(const float4*)(q1 + 4);
                a0[0]=(short)f2bf(v0.x); a0[1]=(short)f2bf(v0.y); a0[2]=(short)f2bf(v0.z); a0[3]=(short)f2bf(v0.w);
                a0[4]=(short)f2bf(v1.x); a0[5]=(short)f2bf(v1.y); a0[6]=(short)f2bf(v1.z); a0[7]=(short)f2bf(v1.w);
                a1[0]=(short)f2bf(u0.x); a1[1]=(short)f2bf(u0.y); a1[2]=(short)f2bf(u0.z); a1[3]=(short)f2bf(u0.w);
                a1[4]=(short)f2bf(u1.x); a1[5]=(short)f2bf(u1.y); a1[6]=(short)f2bf(u1.z); a1[7]=(short)f2bf(u1.w);
            }
            #pragma unroll
            for (int nt = 0; nt < 5; ++nt)
                acc[0][nt] = __builtin_amdgcn_mfma_f32_16x16x32_bf16(a0, bf[nt], acc[0][nt], 0, 0, 0);
            if (has1) {
                #pragma unroll
                for (int nt = 0; nt < 5; ++nt)
                    acc[1][nt] = __builtin_amdgcn_mfma_f32_16x16x32_bf16(a1, bf[nt], acc[1][nt], 0, 0, 0);
            }
        }

        // ---- epilogue per tile ----
        #pragma unroll
        for (int tt = 0; tt < 2; ++tt) {
            if (tt == 1 && !has1) break;
            float part[4] = {0.f, 0.f, 0.f, 0.f};
            #pragma unroll
            for (int nt = 0; nt < 4; ++nt)
                #pragma unroll
                for (int r = 0; r < 4; ++r)
                    part[r] += fmaxf(acc[tt][nt][r] + b1v[nt], 0.f) * w2v[nt];
            #pragma unroll
            for (int r = 0; r < 4; ++r) {
                part[r] += __shfl_xor(part[r], 1);
                part[r] += __shfl_xor(part[r], 2);
                part[r] += __shfl_xor(part[r], 4);
                part[r] += __shfl_xor(part[r], 8);
            }
            if (l15 == 0) {   // t-column acc holds s_j
                const int jg = (tt ? tl1 : tl0) * 16 + quad * 4;
                #pragma unroll
                for (int r = 0; r < 4; ++r) {
                    logit_lds[jg + r] = part[r];
                    s_lds[jg + r]     = acc[tt][4][r];
                }
            }
        }
    }
    __syncthreads();

    // ---- beta-softmax block reduction (rows >= 200 excluded) ----
    float e = 0.f, p = 0.f;
    if (tid < NH) {
        const float ex = (hist_lds[tid] != tgt) ? expf(logit_lds[tid]) : 0.f;
        e = ex;
        p = ex * s_lds[tid];
    }
    #pragma unroll
    for (int off = 32; off > 0; off >>= 1) {
        e += __shfl_down(e, off);
        p += __shfl_down(p, off);
    }
    if (lane == 0) { red_e[wv] = e; red_p[wv] = p; }
    __syncthreads();
    if (tid == 0) {
        const float E = red_e[0] + red_e[1] + red_e[2] + red_e[3];
        const float P = red_p[0] + red_p[1] + red_p[2] + red_p[3];
        const float pred = P / sqrtf(E);      // exp_sum ** 0.5 (BETA = 0.5)
        out[b] = 1.f / (1.f + expf(-pred));
    }
}

extern "C" void kernel_launch(void* const* d_in, const int* in_sizes, int n_in,
                              void* d_out, int out_size, void* d_ws, size_t ws_size,
                              hipStream_t stream) {
    const int*   history        = (const int*)  d_in[0];
    const int*   target         = (const int*)  d_in[1];
    const int*   history_region = (const int*)  d_in[2];
    const int*   target_region  = (const int*)  d_in[3];
    const float* W_hist         = (const float*)d_in[4];
    const float* W_tgt          = (const float*)d_in[5];
    const float* W_reg          = (const float*)d_in[6];
    const float* W1             = (const float*)d_in[7];
    const float* b1             = (const float*)d_in[8];
    const float* W2             = (const float*)d_in[9];
    float* out = (float*)d_out;

    const size_t tab_bytes = (size_t)(HIST_ROWS + REG_ROWS) * 64 * 2;  // 12.93 MB
    const size_t need = tab_bytes + 1024 * 8 * 4;                      // + 32 KB W1F
    if (ws_size >= need) {
        unsigned short* tab = (unsigned short*)d_ws;
        float* W1F = (float*)((char*)d_ws + tab_bytes);
        prep_tables<<<2048, 256, 0, stream>>>(W_hist, W_reg, W1, tab, W1F);
        nais_mfma4<true><<<NB, 256, 0, stream>>>(history, target, history_region, target_region,
                                                 W_hist, W_tgt, W_reg, W1, b1, W2, tab, W1F, out);
    } else {
        nais_mfma4<false><<<NB, 256, 0, stream>>>(history, target, history_region, target_region,
                                                  W_hist, W_tgt, W_reg, W1, b1, W2, nullptr, nullptr, out);
    }
}

// Round 6
// 145.673 us; speedup vs baseline: 1.7005x; 1.7005x over previous
//
#include <hip/hip_runtime.h>
#include <math.h>

// Problem constants (from reference setup_inputs)
#define NB        4096
#define NH        200
#define HIST_ROWS 100000
#define REG_ROWS  1000
#define NTILES    13        // ceil(200/16) M-tiles, M=208

typedef __attribute__((ext_vector_type(8))) short short8;  // 8 bf16 = 4 VGPRs (MFMA A/B frag)
typedef __attribute__((ext_vector_type(4))) float f32x4;   // MFMA C/D frag

// fp32 -> bf16 round-to-nearest-even
__device__ __forceinline__ unsigned short f2bf(float x) {
    union { float f; unsigned u; } v; v.f = x;
    unsigned r = v.u + 0x7FFF + ((v.u >> 16) & 1);
    return (unsigned short)(r >> 16);
}

// Prepass: (a) W_hist|W_reg -> bf16 tables (concat) in ws; (b) block 0 emits
// W1F = W1 in MFMA-fragment order (fp32, 32 KB) for coalesced B' builds.
__global__ __launch_bounds__(256) void prep_tables(
    const float* __restrict__ Wh, const float* __restrict__ Wr,
    const float* __restrict__ W1,
    unsigned short* __restrict__ tab, float* __restrict__ W1F)
{
    const int total4 = (HIST_ROWS + REG_ROWS) * 16;   // float4s
    const int HE4    = HIST_ROWS * 16;
    for (int i = blockIdx.x * blockDim.x + threadIdx.x; i < total4;
         i += gridDim.x * blockDim.x) {
        const float4 v = (i < HE4) ? ((const float4*)Wh)[i]
                                   : ((const float4*)Wr)[i - HE4];
        ushort4 o;
        o.x = f2bf(v.x); o.y = f2bf(v.y); o.z = f2bf(v.z); o.w = f2bf(v.w);
        ((ushort4*)tab)[i] = o;
    }
    if (blockIdx.x == 0) {
        for (int i = threadIdx.x; i < 1024; i += 256) {
            const int frag = i >> 6, c = i & 63;
            const int nt = frag >> 2, ks = frag & 3, q = c >> 4, l = c & 15;
            const int k0 = ks * 32 + q * 8, n = nt * 16 + l;
            float tmp[8];
            #pragma unroll
            for (int j = 0; j < 8; ++j) tmp[j] = W1[(k0 + j) * 64 + n];
            float4* dst = (float4*)(W1F + i * 8);
            dst[0] = make_float4(tmp[0], tmp[1], tmp[2], tmp[3]);
            dst[1] = make_float4(tmp[4], tmp[5], tmp[6], tmp[7]);
        }
    }
}

// epilogue for one M-tile: logit = relu(R+b1).W2 (16-lane xor reduce); s from t-col
__device__ __forceinline__ void epi_store(
    const f32x4* accT, const float* w2v, const float* b1v,
    int tl, int quad, int l15, float* logit_lds, float* s_lds)
{
    float part[4] = {0.f, 0.f, 0.f, 0.f};
    #pragma unroll
    for (int nt = 0; nt < 4; ++nt)
        #pragma unroll
        for (int r = 0; r < 4; ++r)
            part[r] += fmaxf(accT[nt][r] + b1v[nt], 0.f) * w2v[nt];
    #pragma unroll
    for (int r = 0; r < 4; ++r) {
        part[r] += __shfl_xor(part[r], 1);
        part[r] += __shfl_xor(part[r], 2);
        part[r] += __shfl_xor(part[r], 4);
        part[r] += __shfl_xor(part[r], 8);
    }
    if (l15 == 0) {
        const int jg = tl * 16 + quad * 4;
        #pragma unroll
        for (int r = 0; r < 4; ++r) {
            logit_lds[jg + r] = part[r];
            s_lds[jg + r]     = accT[4][r];
        }
    }
}

// One block per b, (256,3): ~168 unified regs/wave — the pressure-feasible
// point (round 2/5 showed 4 waves/SIMD spills, 44-168MB scratch traffic).
// Algebra: inp@W1 = h@(diag(t)W1), s_j = h_j.t -> B' = [t(x)W1 | t] in LDS
// fragment order; A = raw bf16 rows from prepass table.
// Software pipeline: iterA A-frags (8 b128, 32 regs) issued BEFORE the B'
// build so build VALU + barrier drain absorb gather latency; iterB A-frags
// issued before iterA epilogue. acc[2][5] = 40 AGPRs.
template <bool BT>
__global__ __launch_bounds__(256, 3) void nais_mfma5(
    const int*   __restrict__ history,
    const int*   __restrict__ target,
    const int*   __restrict__ history_region,
    const int*   __restrict__ target_region,
    const float* __restrict__ W_hist,
    const float* __restrict__ W_tgt,
    const float* __restrict__ W_reg,
    const float* __restrict__ W1,
    const float* __restrict__ b1,
    const float* __restrict__ W2,
    const unsigned short* __restrict__ tab,   // bf16 tables (BT)
    const float* __restrict__ W1F,            // fragment-ordered W1 (BT)
    float*       __restrict__ out)
{
    __shared__ int hist_lds[224];
    __shared__ int hreg_lds[224];
    __shared__ __align__(16) float t_lds[128];
    __shared__ __align__(16) unsigned short Bf[20 * 512];   // 20 frags x 64 chunks x 8 bf16
    __shared__ float logit_lds[208];
    __shared__ float s_lds[208];
    __shared__ float red_e[4], red_p[4];

    const int b   = blockIdx.x;
    const int tid = threadIdx.x;
    const int tgt = target[b];

    // ---- stage indices (rows 200..223 dup row 199) and t ----
    if (tid < 224) {
        const int jj = tid < NH ? tid : NH - 1;
        hist_lds[tid] = history[b * NH + jj];
        hreg_lds[tid] = history_region[b * NH + jj];
    }
    if (tid < 64) {
        t_lds[tid] = W_tgt[(size_t)tgt * 64 + tid];
    } else if (tid < 128) {
        t_lds[tid] = W_reg[(size_t)target_region[b] * 64 + (tid - 64)];
    }
    __syncthreads();

    const int lane = tid & 63, wv = tid >> 6;
    const int l15  = lane & 15, quad = lane >> 4;

    // ---- this wave's tiles: wv, wv+4, wv+8, wv+12(<13 only for wv==0) ----
    const int  tl0 = wv, tl1 = wv + 4, tl2 = wv + 8, tl3 = wv + 12;
    const bool has3 = (tl3 < NTILES);
    const int  j0 = tl0 * 16 + l15;
    const int  j1 = tl1 * 16 + l15;
    const int  j2 = tl2 * 16 + l15;
    const int  j3 = has3 ? (tl3 * 16 + l15) : j2;

    const unsigned short* tabr = tab + (size_t)HIST_ROWS * 64;
    const unsigned short *p0h, *p0r, *p1h, *p1r, *p2h, *p2r, *p3h, *p3r;
    short8 A0[4], A1[4];
    if (BT) {
        p0h = tab  + (size_t)hist_lds[j0] * 64 + quad * 8;
        p0r = tabr + (size_t)hreg_lds[j0] * 64 + quad * 8;
        p1h = tab  + (size_t)hist_lds[j1] * 64 + quad * 8;
        p1r = tabr + (size_t)hreg_lds[j1] * 64 + quad * 8;
        p2h = tab  + (size_t)hist_lds[j2] * 64 + quad * 8;
        p2r = tabr + (size_t)hreg_lds[j2] * 64 + quad * 8;
        p3h = tab  + (size_t)hist_lds[j3] * 64 + quad * 8;
        p3r = tabr + (size_t)hreg_lds[j3] * 64 + quad * 8;
        // ---- prefetch iterA A-frags NOW: latency hides under B' build ----
        #pragma unroll
        for (int ks = 0; ks < 4; ++ks) {
            A0[ks] = *reinterpret_cast<const short8*>((ks < 2 ? p0h : p0r) + (ks & 1) * 32);
            A1[ks] = *reinterpret_cast<const short8*>((ks < 2 ? p1h : p1r) + (ks & 1) * 32);
        }
    }

    // ---- build B' fragments: chunks 0..1023 = t(x)W1, 1024..1279 = t col ----
    #pragma unroll
    for (int v = 0; v < 4; ++v) {
        const int i  = tid + v * 256;
        const int ks = (i >> 6) & 3, q = (i >> 4) & 3;
        const int k0 = ks * 32 + q * 8;
        const float4 t0 = *(const float4*)(t_lds + k0);
        const float4 t1 = *(const float4*)(t_lds + k0 + 4);
        float4 w0, w1;
        if (BT) {
            w0 = ((const float4*)W1F)[i * 2];
            w1 = ((const float4*)W1F)[i * 2 + 1];
        } else {
            const int nt = i >> 8, l = i & 15, n = nt * 16 + l;
            float tmp[8];
            #pragma unroll
            for (int j = 0; j < 8; ++j) tmp[j] = W1[(k0 + j) * 64 + n];
            w0 = make_float4(tmp[0], tmp[1], tmp[2], tmp[3]);
            w1 = make_float4(tmp[4], tmp[5], tmp[6], tmp[7]);
        }
        short8 o;
        o[0] = (short)f2bf(w0.x * t0.x); o[1] = (short)f2bf(w0.y * t0.y);
        o[2] = (short)f2bf(w0.z * t0.z); o[3] = (short)f2bf(w0.w * t0.w);
        o[4] = (short)f2bf(w1.x * t1.x); o[5] = (short)f2bf(w1.y * t1.y);
        o[6] = (short)f2bf(w1.z * t1.z); o[7] = (short)f2bf(w1.w * t1.w);
        *reinterpret_cast<short8*>(&Bf[i * 8]) = o;
    }
    {
        const int i  = 1024 + tid;
        const int ks = tid >> 6, c = tid & 63, q = c >> 4, l = c & 15;
        const int k0 = ks * 32 + q * 8;
        short8 o;
        #pragma unroll
        for (int j = 0; j < 8; ++j)
            o[j] = (l == 0) ? (short)f2bf(t_lds[k0 + j]) : (short)0;
        *reinterpret_cast<short8*>(&Bf[i * 8]) = o;
    }
    __syncthreads();   // barrier drain also completes the A0/A1 prefetch

    float w2v[4], b1v[4];
    #pragma unroll
    for (int nt = 0; nt < 4; ++nt) {
        w2v[nt] = W2[nt * 16 + l15];
        b1v[nt] = b1[nt * 16 + l15];
    }

    f32x4 acc[2][5];
    #pragma unroll
    for (int tt = 0; tt < 2; ++tt)
        #pragma unroll
        for (int nt = 0; nt < 5; ++nt) acc[tt][nt] = (f32x4){0.f, 0.f, 0.f, 0.f};

    // ---- iterA MFMA (tiles tl0, tl1) ----
    #pragma unroll
    for (int ks = 0; ks < 4; ++ks) {
        short8 bf[5];
        #pragma unroll
        for (int nt = 0; nt < 5; ++nt)
            bf[nt] = *reinterpret_cast<const short8*>(
                &Bf[((nt * 4 + ks) * 64 + quad * 16 + l15) * 8]);
        if (!BT) {
            const float* q0 = ((ks < 2) ? (W_hist + (size_t)hist_lds[j0] * 64)
                                        : (W_reg  + (size_t)hreg_lds[j0] * 64)) + quad * 8 + (ks & 1) * 32;
            const float* q1 = ((ks < 2) ? (W_hist + (size_t)hist_lds[j1] * 64)
                                        : (W_reg  + (size_t)hreg_lds[j1] * 64)) + quad * 8 + (ks & 1) * 32;
            const float4 v0 = *(const float4*)q0, v1 = *(const float4*)(q0 + 4);
            const float4 u0 = *(const float4*)q1, u1 = *(const float4*)(q1 + 4);
            A0[ks][0]=(short)f2bf(v0.x); A0[ks][1]=(short)f2bf(v0.y); A0[ks][2]=(short)f2bf(v0.z); A0[ks][3]=(short)f2bf(v0.w);
            A0[ks][4]=(short)f2bf(v1.x); A0[ks][5]=(short)f2bf(v1.y); A0[ks][6]=(short)f2bf(v1.z); A0[ks][7]=(short)f2bf(v1.w);
            A1[ks][0]=(short)f2bf(u0.x); A1[ks][1]=(short)f2bf(u0.y); A1[ks][2]=(short)f2bf(u0.z); A1[ks][3]=(short)f2bf(u0.w);
            A1[ks][4]=(short)f2bf(u1.x); A1[ks][5]=(short)f2bf(u1.y); A1[ks][6]=(short)f2bf(u1.z); A1[ks][7]=(short)f2bf(u1.w);
        }
        #pragma unroll
        for (int nt = 0; nt < 5; ++nt)
            acc[0][nt] = __builtin_amdgcn_mfma_f32_16x16x32_bf16(A0[ks], bf[nt], acc[0][nt], 0, 0, 0);
        #pragma unroll
        for (int nt = 0; nt < 5; ++nt)
            acc[1][nt] = __builtin_amdgcn_mfma_f32_16x16x32_bf16(A1[ks], bf[nt], acc[1][nt], 0, 0, 0);
    }

    // ---- issue iterB loads; epilogue A overlaps their latency ----
    short8 A2[4], A3[4];
    if (BT) {
        #pragma unroll
        for (int ks = 0; ks < 4; ++ks) {
            A2[ks] = *reinterpret_cast<const short8*>((ks < 2 ? p2h : p2r) + (ks & 1) * 32);
            A3[ks] = *reinterpret_cast<const short8*>((ks < 2 ? p3h : p3r) + (ks & 1) * 32);
        }
    }

    epi_store(acc[0], w2v, b1v, tl0, quad, l15, logit_lds, s_lds);
    epi_store(acc[1], w2v, b1v, tl1, quad, l15, logit_lds, s_lds);

    #pragma unroll
    for (int tt = 0; tt < 2; ++tt)
        #pragma unroll
        for (int nt = 0; nt < 5; ++nt) acc[tt][nt] = (f32x4){0.f, 0.f, 0.f, 0.f};

    // ---- iterB MFMA (tiles tl2, tl3 if valid) ----
    #pragma unroll
    for (int ks = 0; ks < 4; ++ks) {
        short8 bf[5];
        #pragma unroll
        for (int nt = 0; nt < 5; ++nt)
            bf[nt] = *reinterpret_cast<const short8*>(
                &Bf[((nt * 4 + ks) * 64 + quad * 16 + l15) * 8]);
        if (!BT) {
            const float* q0 = ((ks < 2) ? (W_hist + (size_t)hist_lds[j2] * 64)
                                        : (W_reg  + (size_t)hreg_lds[j2] * 64)) + quad * 8 + (ks & 1) * 32;
            const float* q1 = ((ks < 2) ? (W_hist + (size_t)hist_lds[j3] * 64)
                                        : (W_reg  + (size_t)hreg_lds[j3] * 64)) + quad * 8 + (ks & 1) * 32;
            const float4 v0 = *(const float4*)q0, v1 = *(const float4*)(q0 + 4);
            const float4 u0 = *(const float4*)q1, u1 = *(const float4*)(q1 + 4);
            A2[ks][0]=(short)f2bf(v0.x); A2[ks][1]=(short)f2bf(v0.y); A2[ks][2]=(short)f2bf(v0.z); A2[ks][3]=(short)f2bf(v0.w);
            A2[ks][4]=(short)f2bf(v1.x); A2[ks][5]=(short)f2bf(v1.y); A2[ks][6]=(short)f2bf(v1.z); A2[ks][7]=(short)f2bf(v1.w);
            A3[ks][0]=(short)f2bf(u0.x); A3[ks][1]=(short)f2bf(u0.y); A3[ks][2]=(short)f2bf(u0.z); A3[ks][3]=(short)f2bf(u0.w);
            A3[ks][4]=(short)f2bf(u1.x); A3[ks][5]=(short)f2bf(u1.y); A3[ks][6]=(short)f2bf(u1.z); A3[ks][7]=(short)f2bf(u1.w);
        }
        #pragma unroll
        for (int nt = 0; nt < 5; ++nt)
            acc[0][nt] = __builtin_amdgcn_mfma_f32_16x16x32_bf16(A2[ks], bf[nt], acc[0][nt], 0, 0, 0);
        if (has3) {
            #pragma unroll
            for (int nt = 0; nt < 5; ++nt)
                acc[1][nt] = __builtin_amdgcn_mfma_f32_16x16x32_bf16(A3[ks], bf[nt], acc[1][nt], 0, 0, 0);
        }
    }

    epi_store(acc[0], w2v, b1v, tl2, quad, l15, logit_lds, s_lds);
    if (has3) epi_store(acc[1], w2v, b1v, tl3, quad, l15, logit_lds, s_lds);
    __syncthreads();

    // ---- beta-softmax block reduction (rows >= 200 excluded) ----
    float e = 0.f, p = 0.f;
    if (tid < NH) {
        const float ex = (hist_lds[tid] != tgt) ? expf(logit_lds[tid]) : 0.f;
        e = ex;
        p = ex * s_lds[tid];
    }
    #pragma unroll
    for (int off = 32; off > 0; off >>= 1) {
        e += __shfl_down(e, off);
        p += __shfl_down(p, off);
    }
    if (lane == 0) { red_e[wv] = e; red_p[wv] = p; }
    __syncthreads();
    if (tid == 0) {
        const float E = red_e[0] + red_e[1] + red_e[2] + red_e[3];
        const float P = red_p[0] + red_p[1] + red_p[2] + red_p[3];
        const float pred = P / sqrtf(E);      // exp_sum ** 0.5 (BETA = 0.5)
        out[b] = 1.f / (1.f + expf(-pred));
    }
}

extern "C" void kernel_launch(void* const* d_in, const int* in_sizes, int n_in,
                              void* d_out, int out_size, void* d_ws, size_t ws_size,
                              hipStream_t stream) {
    const int*   history        = (const int*)  d_in[0];
    const int*   target         = (const int*)  d_in[1];
    const int*   history_region = (const int*)  d_in[2];
    const int*   target_region  = (const int*)  d_in[3];
    const float* W_hist         = (const float*)d_in[4];
    const float* W_tgt          = (const float*)d_in[5];
    const float* W_reg          = (const float*)d_in[6];
    const float* W1             = (const float*)d_in[7];
    const float* b1             = (const float*)d_in[8];
    const float* W2             = (const float*)d_in[9];
    float* out = (float*)d_out;

    const size_t tab_bytes = (size_t)(HIST_ROWS + REG_ROWS) * 64 * 2;  // 12.93 MB
    const size_t need = tab_bytes + 1024 * 8 * 4;                      // + 32 KB W1F
    if (ws_size >= need) {
        unsigned short* tab = (unsigned short*)d_ws;
        float* W1F = (float*)((char*)d_ws + tab_bytes);
        prep_tables<<<2048, 256, 0, stream>>>(W_hist, W_reg, W1, tab, W1F);
        nais_mfma5<true><<<NB, 256, 0, stream>>>(history, target, history_region, target_region,
                                                 W_hist, W_tgt, W_reg, W1, b1, W2, tab, W1F, out);
    } else {
        nais_mfma5<false><<<NB, 256, 0, stream>>>(history, target, history_region, target_region,
                                                  W_hist, W_tgt, W_reg, W1, b1, W2, nullptr, nullptr, out);
    }
}